// Round 12
// baseline (63.001 us; speedup 1.0000x reference)
//
#include <hip/hip_runtime.h>

#define BB 2048
#define EMB 128
#define NF 200
#define W_OUT 126
#define EPS 1e-5f

// ws: A-matrix f16, 832 rows (800 real + 32 zero-pad) x 32 taps = 53248 B
// d_out[0:1024): G32 Gram scratch (memset -> stats atomics -> finalize),
//                fully overwritten by main afterwards.
#define AW_OFF 0
#define MT_PAD 52                 // padded M tiles (832 rows)

#define SPBS 4                    // stats: samples per block (wave <-> sample)
#define STATS_BLOCKS (BB / SPBS)  // 512
#define SPBM 4                    // main: samples per block, waves split M
#define MAIN_BLOCKS (BB / SPBM)   // 512

typedef _Float16 half8 __attribute__((ext_vector_type(8)));
typedef float f32x4v __attribute__((ext_vector_type(4)));

__device__ __forceinline__ const float* rowptr(const int* __restrict__ xr, int r,
                                               const float* __restrict__ er,
                                               const float* __restrict__ ev) {
  if (r == 0) return ev + (size_t)xr[1] * EMB;
  if (r == 1) return er + (size_t)xr[0] * EMB;
  if (r == 2) return ev + (size_t)xr[3] * EMB;
  const int k = (r - 3) >> 1;
  return ((r - 3) & 1) ? ev + (size_t)xr[5 + 2 * k] * EMB
                       : er + (size_t)xr[4 + 2 * k] * EMB;
}

// ---------------- stats: G32 = sum_s B_s^T B_s via MFMA (proven) ------------
__global__ __launch_bounds__(256, 2) void stats_mfma(
    const int* __restrict__ xb, const float* __restrict__ er,
    const float* __restrict__ ev, float* __restrict__ gout) {
  __shared__ _Float16 Bt[SPBS][40][136];   // 42.5 KB
  __shared__ float Gred[SPBS][1024];       // 16 KB
  const int tid = threadIdx.x;
  const int base = blockIdx.x * SPBS;

  for (int job = tid; job < SPBS * 136; job += 256) {
    const int s = job / 136, x = job % 136;
    if (x < W_OUT) {
      const int* xr = xb + (size_t)(base + s) * 10;
#pragma unroll
      for (int r = 0; r < 9; r++) {
        const float* hp = rowptr(xr, r, er, ev);
        Bt[s][3 * r + 0][x] = (_Float16)hp[x];
        Bt[s][3 * r + 1][x] = (_Float16)hp[x + 1];
        Bt[s][3 * r + 2][x] = (_Float16)hp[x + 2];
      }
      Bt[s][27][x] = (_Float16)1.0f;
#pragma unroll
      for (int k = 28; k < 40; k++) Bt[s][k][x] = (_Float16)0.f;
    } else {
#pragma unroll
      for (int k = 0; k < 40; k++) Bt[s][k][x] = (_Float16)0.f;
    }
  }
  __syncthreads();

  const int w = tid >> 6, l = tid & 63;
  const int tl = l & 15, kl = l >> 4;
  f32x4v a00 = {0.f, 0.f, 0.f, 0.f}, a01 = a00, a10 = a00, a11 = a00;
#pragma unroll
  for (int c = 0; c < 4; c++) {
    const int x0 = c * 32 + kl * 8;
    const half8 g0 = *(const half8*)&Bt[w][tl][x0];       // taps 0..15
    const half8 g1 = *(const half8*)&Bt[w][16 + tl][x0];  // taps 16..31
    a00 = __builtin_amdgcn_mfma_f32_16x16x32_f16(g0, g0, a00, 0, 0, 0);
    a01 = __builtin_amdgcn_mfma_f32_16x16x32_f16(g0, g1, a01, 0, 0, 0);
    a10 = __builtin_amdgcn_mfma_f32_16x16x32_f16(g1, g0, a10, 0, 0, 0);
    a11 = __builtin_amdgcn_mfma_f32_16x16x32_f16(g1, g1, a11, 0, 0, 0);
  }
  // D layout: row=(l>>4)*4+reg, col=l&15
#pragma unroll
  for (int r = 0; r < 4; r++) {
    const int rm = kl * 4 + r;
    Gred[w][rm * 32 + tl]             = a00[r];
    Gred[w][rm * 32 + 16 + tl]        = a01[r];
    Gred[w][(16 + rm) * 32 + tl]      = a10[r];
    Gred[w][(16 + rm) * 32 + 16 + tl] = a11[r];
  }
  __syncthreads();
  for (int idx = tid; idx < 1024; idx += 256) {
    float s = Gred[0][idx] + Gred[1][idx] + Gred[2][idx] + Gred[3][idx];
    atomicAdd(&gout[idx], s);
  }
}

// ---------------- finalize: G32 -> BN params -> f16 A-matrix ----------------
__global__ __launch_bounds__(256) void finalize_kernel(
    const float* __restrict__ w1, const float* __restrict__ w2,
    const float* __restrict__ g1, const float* __restrict__ be1,
    const float* __restrict__ g2, const float* __restrict__ be2,
    const float* __restrict__ gbuf, float* __restrict__ ws) {
  __shared__ float G[1024];
  const int tid = threadIdx.x;
  for (int e = tid; e < 1024; e += 256) G[e] = gbuf[e];
  __syncthreads();
  const int f = tid;
  _Float16* Aw = (_Float16*)ws + AW_OFF;
  if (f >= NF) {
    if (f < 208) {                 // zero the pad rows 800..831
      _Float16* rw = Aw + (size_t)(4 * f) * 32;
      for (int k = 0; k < 128; k++) rw[k] = (_Float16)0.f;
    }
    return;
  }
  float w1r[9], w2r[15];
#pragma unroll
  for (int j = 0; j < 9; j++)  w1r[j] = w1[f * 9 + j];
#pragma unroll
  for (int j = 0; j < 15; j++) w2r[j] = w2[f * 15 + j];
  const float invN = 1.0f / (float)(BB * W_OUT);

  float m1 = 0.f, q1 = 0.f;
#pragma unroll
  for (int i = 0; i < 9; i++) {
    m1 = fmaf(w1r[i], G[i * 32 + 27], m1);
#pragma unroll
    for (int j = 0; j < 9; j++) q1 = fmaf(w1r[i] * w1r[j], G[i * 32 + j], q1);
  }
  m1 *= invN;
  float v1 = q1 * invN - m1 * m1;
  float sc1 = g1[f] * rsqrtf(v1 + EPS);
  float sh1 = be1[f] - m1 * sc1;
  {
    _Float16* rw = Aw + (size_t)(4 * f + 0) * 32;
#pragma unroll
    for (int k = 0; k < 32; k++) rw[k] = (_Float16)0.f;
#pragma unroll
    for (int i = 0; i < 9; i++) rw[i] = (_Float16)(w1r[i] * sc1);
    rw[27] = (_Float16)sh1;
  }

  float mcm = 0.f, qc = 0.f;
#pragma unroll
  for (int i = 0; i < 9; i++) {
    mcm = fmaf(w2r[i], G[i * 32 + 27], mcm);
#pragma unroll
    for (int j = 0; j < 9; j++) qc = fmaf(w2r[i] * w2r[j], G[i * 32 + j], qc);
  }
#pragma unroll
  for (int kk = 0; kk < 3; kk++) {
    const int a = 3 + 2 * kk, b = 4 + 2 * kk;
    float m2 = mcm, cross = 0.f, qa = 0.f, qb = 0.f, qab = 0.f;
#pragma unroll
    for (int j = 0; j < 3; j++) {
      m2 = fmaf(w2r[9 + j],  G[(3 * a + j) * 32 + 27], m2);
      m2 = fmaf(w2r[12 + j], G[(3 * b + j) * 32 + 27], m2);
    }
#pragma unroll
    for (int i = 0; i < 9; i++) {
      float t = 0.f;
#pragma unroll
      for (int j = 0; j < 3; j++) {
        t = fmaf(w2r[9 + j],  G[i * 32 + 3 * a + j], t);
        t = fmaf(w2r[12 + j], G[i * 32 + 3 * b + j], t);
      }
      cross = fmaf(w2r[i], t, cross);
    }
#pragma unroll
    for (int j = 0; j < 3; j++)
#pragma unroll
      for (int jp = 0; jp < 3; jp++) {
        qa  = fmaf(w2r[9 + j]  * w2r[9 + jp],  G[(3 * a + j) * 32 + 3 * a + jp], qa);
        qb  = fmaf(w2r[12 + j] * w2r[12 + jp], G[(3 * b + j) * 32 + 3 * b + jp], qb);
        qab = fmaf(w2r[9 + j]  * w2r[12 + jp], G[(3 * a + j) * 32 + 3 * b + jp], qab);
      }
    float q2 = qc + 2.f * cross + qa + qb + 2.f * qab;
    float mean2 = m2 * invN;
    float v2 = q2 * invN - mean2 * mean2;
    float sck = g2[f] * rsqrtf(v2 + EPS);
    float shk = be2[f] - mean2 * sck;

    _Float16* rw = Aw + (size_t)(4 * f + 1 + kk) * 32;
#pragma unroll
    for (int k = 0; k < 32; k++) rw[k] = (_Float16)0.f;
#pragma unroll
    for (int i = 0; i < 9; i++) rw[i] = (_Float16)(w2r[i] * sck);
#pragma unroll
    for (int j = 0; j < 3; j++) {
      rw[3 * a + j] = (_Float16)(w2r[9 + j]  * sck);
      rw[3 * b + j] = (_Float16)(w2r[12 + j] * sck);
    }
    rw[27] = (_Float16)shk;
  }
}

// ---------------- main: 4 samples/block, waves split M; A & fcw shared ------
__global__ __launch_bounds__(256, 4) void main_mfma(
    const int* __restrict__ xb, const float* __restrict__ er,
    const float* __restrict__ ev, const float* __restrict__ fcw,
    const float* __restrict__ fcb, const float* __restrict__ ws,
    float* __restrict__ out) {
  __shared__ _Float16 Bm[SPBM][128][40];   // 40 KB
  __shared__ float red[4][SPBM];           // [wave][sample]
  const int tid = threadIdx.x;
  const int base = blockIdx.x * SPBM;

  // B build: 512 jobs, 2 per thread
  for (int job = tid; job < SPBM * 128; job += 256) {
    const int s = job >> 7, x = job & 127;
    const int* xr = xb + (size_t)(base + s) * 10;
    const int x1 = (x + 1 < 128) ? x + 1 : 127;   // cols >= W_OUT masked by fcv
    const int x2 = (x + 2 < 128) ? x + 2 : 127;
    _Float16* dst = &Bm[s][x][0];
#pragma unroll
    for (int r = 0; r < 9; r++) {
      const float* hp = rowptr(xr, r, er, ev);
      dst[3 * r + 0] = (_Float16)hp[x];
      dst[3 * r + 1] = (_Float16)hp[x1];
      dst[3 * r + 2] = (_Float16)hp[x2];
    }
    dst[27] = (_Float16)1.0f;
#pragma unroll
    for (int k = 28; k < 40; k++) dst[k] = (_Float16)0.f;
  }
  __syncthreads();

  const int w = tid >> 6, l = tid & 63;
  const int xl = l & 15, fl = l >> 4;
  const _Float16* __restrict__ Aw = (const _Float16*)ws + AW_OFF;
  const float fcb0 = fcb[0];

  float psum0 = 0.f, psum1 = 0.f, psum2 = 0.f, psum3 = 0.f;
#pragma unroll 1
  for (int jh = 0; jh < 2; ++jh) {
    // 16 resident B frags: 4 samples x 4 N-tiles (64 VGPR)
    half8 bf[4][4];
#pragma unroll
    for (int s = 0; s < 4; ++s)
#pragma unroll
      for (int j = 0; j < 4; ++j)
        bf[s][j] = *(const half8*)&Bm[s][(jh * 4 + j) * 16 + xl][fl * 8];

#pragma unroll 1
    for (int mt = 0; mt < 13; ++mt) {
      const int mtile = w * 13 + mt;              // waves split M (52 tiles)
      const half8 af = *(const half8*)&Aw[(size_t)(mtile * 16 + xl) * 32 + fl * 8];
      const int f = mtile * 4 + fl;               // D row=(l>>4)*4+reg = 4f+conv
      const bool fv = (f < NF);
      const int fi = fv ? f : 0;
#pragma unroll
      for (int j = 0; j < 4; ++j) {
        const int x = (jh * 4 + j) * 16 + xl;
        const bool xv = fv && (x < W_OUT);
        const float fcl = fcw[(size_t)fi * W_OUT + (x < W_OUT ? x : 0)];
        const float fcv = xv ? fcl : 0.f;         // shared by all 4 samples
        f32x4v a0 = __builtin_amdgcn_mfma_f32_16x16x32_f16(
            af, bf[0][j], (f32x4v){0.f, 0.f, 0.f, 0.f}, 0, 0, 0);
        f32x4v a1 = __builtin_amdgcn_mfma_f32_16x16x32_f16(
            af, bf[1][j], (f32x4v){0.f, 0.f, 0.f, 0.f}, 0, 0, 0);
        f32x4v a2 = __builtin_amdgcn_mfma_f32_16x16x32_f16(
            af, bf[2][j], (f32x4v){0.f, 0.f, 0.f, 0.f}, 0, 0, 0);
        f32x4v a3 = __builtin_amdgcn_mfma_f32_16x16x32_f16(
            af, bf[3][j], (f32x4v){0.f, 0.f, 0.f, 0.f}, 0, 0, 0);
        float m0 = fminf(fminf(a0[0], a0[1]), fminf(a0[2], a0[3]));
        float m1 = fminf(fminf(a1[0], a1[1]), fminf(a1[2], a1[3]));
        float m2 = fminf(fminf(a2[0], a2[1]), fminf(a2[2], a2[3]));
        float m3 = fminf(fminf(a3[0], a3[1]), fminf(a3[2], a3[3]));
        psum0 = fmaf(fmaxf(m0, 0.f), fcv, psum0); // min(relu)=relu(min)
        psum1 = fmaf(fmaxf(m1, 0.f), fcv, psum1);
        psum2 = fmaf(fmaxf(m2, 0.f), fcv, psum2);
        psum3 = fmaf(fmaxf(m3, 0.f), fcv, psum3);
      }
    }
  }

#pragma unroll
  for (int off = 32; off; off >>= 1) {
    psum0 += __shfl_xor(psum0, off, 64);
    psum1 += __shfl_xor(psum1, off, 64);
    psum2 += __shfl_xor(psum2, off, 64);
    psum3 += __shfl_xor(psum3, off, 64);
  }
  if (l == 0) {
    red[w][0] = psum0; red[w][1] = psum1; red[w][2] = psum2; red[w][3] = psum3;
  }
  __syncthreads();
  if (tid < SPBM)
    out[base + tid] = red[0][tid] + red[1][tid] + red[2][tid] + red[3][tid] + fcb0;
}

extern "C" void kernel_launch(void* const* d_in, const int* in_sizes, int n_in,
                              void* d_out, int out_size, void* d_ws, size_t ws_size,
                              hipStream_t stream) {
  const int* xb    = (const int*)d_in[0];
  const float* er  = (const float*)d_in[3];
  const float* ev  = (const float*)d_in[4];
  const float* w1  = (const float*)d_in[5];
  const float* g1  = (const float*)d_in[7];
  const float* be1 = (const float*)d_in[8];
  const float* w2  = (const float*)d_in[9];
  const float* g2  = (const float*)d_in[11];
  const float* be2 = (const float*)d_in[12];
  const float* fcw = (const float*)d_in[13];
  const float* fcb = (const float*)d_in[14];
  float* ws  = (float*)d_ws;
  float* out = (float*)d_out;

  // G32 scratch = out[0:1024) (overwritten by main afterwards)
  hipMemsetAsync(out, 0, 1024 * sizeof(float), stream);
  hipLaunchKernelGGL(stats_mfma, dim3(STATS_BLOCKS), dim3(256), 0, stream,
                     xb, er, ev, out);
  hipLaunchKernelGGL(finalize_kernel, dim3(1), dim3(256), 0, stream,
                     w1, w2, g1, be1, g2, be2, out, ws);
  hipLaunchKernelGGL(main_mfma, dim3(MAIN_BLOCKS), dim3(256), 0, stream,
                     xb, er, ev, fcw, fcb, ws, out);
}

// Round 13
// 57.372 us; speedup vs baseline: 1.0981x; 1.0981x over previous
//
#include <hip/hip_runtime.h>

#define BB 2048
#define EMB 128
#define NF 200
#define W_OUT 126
#define EPS 1e-5f

// ws layout (bytes):
// [0, 51200)        A-matrix f16 (800 rows x 32 taps)
// [51200, 153600)   fcwQ: swizzled fc weights, [50][2][64][4] float
// d_out[0:1024): G32 Gram scratch (memset -> stats atomics -> finalize),
//                fully overwritten by main afterwards.
#define AW_OFF 0
#define FCWQ_BYTE_OFF 51200
#define FCWQ_FLOATS (50 * 2 * 64 * 4)   // 25600
#define WS_NEED (FCWQ_BYTE_OFF + FCWQ_FLOATS * 4)

#define SPBS 4                    // stats: samples per block (wave <-> sample)
#define STATS_BLOCKS (BB / SPBS)  // 512
#define SPBM 2                    // main: samples per block (2 waves each)
#define MAIN_BLOCKS (BB / SPBM)   // 1024

typedef _Float16 half8 __attribute__((ext_vector_type(8)));
typedef float f32x4v __attribute__((ext_vector_type(4)));

__device__ __forceinline__ const float* rowptr(const int* __restrict__ xr, int r,
                                               const float* __restrict__ er,
                                               const float* __restrict__ ev) {
  if (r == 0) return ev + (size_t)xr[1] * EMB;
  if (r == 1) return er + (size_t)xr[0] * EMB;
  if (r == 2) return ev + (size_t)xr[3] * EMB;
  const int k = (r - 3) >> 1;
  return ((r - 3) & 1) ? ev + (size_t)xr[5 + 2 * k] * EMB
                       : er + (size_t)xr[4 + 2 * k] * EMB;
}

// ---------------- stats: G32 = sum_s B_s^T B_s via MFMA (proven) ------------
__global__ __launch_bounds__(256, 2) void stats_mfma(
    const int* __restrict__ xb, const float* __restrict__ er,
    const float* __restrict__ ev, float* __restrict__ gout) {
  __shared__ _Float16 Bt[SPBS][40][136];   // 42.5 KB
  __shared__ float Gred[SPBS][1024];       // 16 KB
  const int tid = threadIdx.x;
  const int base = blockIdx.x * SPBS;

  for (int job = tid; job < SPBS * 136; job += 256) {
    const int s = job / 136, x = job % 136;
    if (x < W_OUT) {
      const int* xr = xb + (size_t)(base + s) * 10;
#pragma unroll
      for (int r = 0; r < 9; r++) {
        const float* hp = rowptr(xr, r, er, ev);
        Bt[s][3 * r + 0][x] = (_Float16)hp[x];
        Bt[s][3 * r + 1][x] = (_Float16)hp[x + 1];
        Bt[s][3 * r + 2][x] = (_Float16)hp[x + 2];
      }
      Bt[s][27][x] = (_Float16)1.0f;
#pragma unroll
      for (int k = 28; k < 40; k++) Bt[s][k][x] = (_Float16)0.f;
    } else {
#pragma unroll
      for (int k = 0; k < 40; k++) Bt[s][k][x] = (_Float16)0.f;
    }
  }
  __syncthreads();

  const int w = tid >> 6, l = tid & 63;
  const int tl = l & 15, kl = l >> 4;
  f32x4v a00 = {0.f, 0.f, 0.f, 0.f}, a01 = a00, a10 = a00, a11 = a00;
#pragma unroll
  for (int c = 0; c < 4; c++) {
    const int x0 = c * 32 + kl * 8;
    const half8 g0 = *(const half8*)&Bt[w][tl][x0];       // taps 0..15
    const half8 g1 = *(const half8*)&Bt[w][16 + tl][x0];  // taps 16..31
    a00 = __builtin_amdgcn_mfma_f32_16x16x32_f16(g0, g0, a00, 0, 0, 0);
    a01 = __builtin_amdgcn_mfma_f32_16x16x32_f16(g0, g1, a01, 0, 0, 0);
    a10 = __builtin_amdgcn_mfma_f32_16x16x32_f16(g1, g0, a10, 0, 0, 0);
    a11 = __builtin_amdgcn_mfma_f32_16x16x32_f16(g1, g1, a11, 0, 0, 0);
  }
  // D layout: row=(l>>4)*4+reg, col=l&15
#pragma unroll
  for (int r = 0; r < 4; r++) {
    const int rm = kl * 4 + r;
    Gred[w][rm * 32 + tl]             = a00[r];
    Gred[w][rm * 32 + 16 + tl]        = a01[r];
    Gred[w][(16 + rm) * 32 + tl]      = a10[r];
    Gred[w][(16 + rm) * 32 + 16 + tl] = a11[r];
  }
  __syncthreads();
  for (int idx = tid; idx < 1024; idx += 256) {
    float s = Gred[0][idx] + Gred[1][idx] + Gred[2][idx] + Gred[3][idx];
    atomicAdd(&gout[idx], s);
  }
}

// ---------------- fcw swizzle: bake MFMA lane order + masks -----------------
__global__ __launch_bounds__(256) void swizzle_fcw(
    const float* __restrict__ fcw, float* __restrict__ fcwQ) {
  const int idx = blockIdx.x * 256 + threadIdx.x;
  if (idx >= FCWQ_FLOATS) return;
  const int mtile = idx >> 9;          // /512
  const int rem = idx & 511;
  const int jh = rem >> 8;             // /256
  const int rem2 = rem & 255;
  const int l = rem2 >> 2;
  const int j = rem2 & 3;
  const int f = mtile * 4 + (l >> 4);  // always < 200
  const int x = (jh * 4 + j) * 16 + (l & 15);
  fcwQ[idx] = (x < W_OUT) ? fcw[(size_t)f * W_OUT + x] : 0.f;
}

// ---------------- finalize: G32 -> BN params -> f16 A-matrix ----------------
__global__ __launch_bounds__(256) void finalize_kernel(
    const float* __restrict__ w1, const float* __restrict__ w2,
    const float* __restrict__ g1, const float* __restrict__ be1,
    const float* __restrict__ g2, const float* __restrict__ be2,
    const float* __restrict__ gbuf, float* __restrict__ ws) {
  __shared__ float G[1024];
  const int tid = threadIdx.x;
  for (int e = tid; e < 1024; e += 256) G[e] = gbuf[e];
  __syncthreads();
  const int f = tid;
  if (f >= NF) return;
  _Float16* Aw = (_Float16*)ws + AW_OFF;
  float w1r[9], w2r[15];
#pragma unroll
  for (int j = 0; j < 9; j++)  w1r[j] = w1[f * 9 + j];
#pragma unroll
  for (int j = 0; j < 15; j++) w2r[j] = w2[f * 15 + j];
  const float invN = 1.0f / (float)(BB * W_OUT);

  float m1 = 0.f, q1 = 0.f;
#pragma unroll
  for (int i = 0; i < 9; i++) {
    m1 = fmaf(w1r[i], G[i * 32 + 27], m1);
#pragma unroll
    for (int j = 0; j < 9; j++) q1 = fmaf(w1r[i] * w1r[j], G[i * 32 + j], q1);
  }
  m1 *= invN;
  float v1 = q1 * invN - m1 * m1;
  float sc1 = g1[f] * rsqrtf(v1 + EPS);
  float sh1 = be1[f] - m1 * sc1;
  {
    _Float16* rw = Aw + (size_t)(4 * f + 0) * 32;
#pragma unroll
    for (int k = 0; k < 32; k++) rw[k] = (_Float16)0.f;
#pragma unroll
    for (int i = 0; i < 9; i++) rw[i] = (_Float16)(w1r[i] * sc1);
    rw[27] = (_Float16)sh1;
  }

  float mcm = 0.f, qc = 0.f;
#pragma unroll
  for (int i = 0; i < 9; i++) {
    mcm = fmaf(w2r[i], G[i * 32 + 27], mcm);
#pragma unroll
    for (int j = 0; j < 9; j++) qc = fmaf(w2r[i] * w2r[j], G[i * 32 + j], qc);
  }
#pragma unroll
  for (int kk = 0; kk < 3; kk++) {
    const int a = 3 + 2 * kk, b = 4 + 2 * kk;
    float m2 = mcm, cross = 0.f, qa = 0.f, qb = 0.f, qab = 0.f;
#pragma unroll
    for (int j = 0; j < 3; j++) {
      m2 = fmaf(w2r[9 + j],  G[(3 * a + j) * 32 + 27], m2);
      m2 = fmaf(w2r[12 + j], G[(3 * b + j) * 32 + 27], m2);
    }
#pragma unroll
    for (int i = 0; i < 9; i++) {
      float t = 0.f;
#pragma unroll
      for (int j = 0; j < 3; j++) {
        t = fmaf(w2r[9 + j],  G[i * 32 + 3 * a + j], t);
        t = fmaf(w2r[12 + j], G[i * 32 + 3 * b + j], t);
      }
      cross = fmaf(w2r[i], t, cross);
    }
#pragma unroll
    for (int j = 0; j < 3; j++)
#pragma unroll
      for (int jp = 0; jp < 3; jp++) {
        qa  = fmaf(w2r[9 + j]  * w2r[9 + jp],  G[(3 * a + j) * 32 + 3 * a + jp], qa);
        qb  = fmaf(w2r[12 + j] * w2r[12 + jp], G[(3 * b + j) * 32 + 3 * b + jp], qb);
        qab = fmaf(w2r[9 + j]  * w2r[12 + jp], G[(3 * a + j) * 32 + 3 * b + jp], qab);
      }
    float q2 = qc + 2.f * cross + qa + qb + 2.f * qab;
    float mean2 = m2 * invN;
    float v2 = q2 * invN - mean2 * mean2;
    float sck = g2[f] * rsqrtf(v2 + EPS);
    float shk = be2[f] - mean2 * sck;

    _Float16* rw = Aw + (size_t)(4 * f + 1 + kk) * 32;
#pragma unroll
    for (int k = 0; k < 32; k++) rw[k] = (_Float16)0.f;
#pragma unroll
    for (int i = 0; i < 9; i++) rw[i] = (_Float16)(w2r[i] * sck);
#pragma unroll
    for (int j = 0; j < 3; j++) {
      rw[3 * a + j] = (_Float16)(w2r[9 + j]  * sck);
      rw[3 * b + j] = (_Float16)(w2r[12 + j] * sck);
    }
    rw[27] = (_Float16)shk;
  }
}

// ---------------- main: R11 loop nest + swizzled coalesced fcwQ -------------
template <bool SWZ>
__global__ __launch_bounds__(256, 4) void main_mfma(
    const int* __restrict__ xb, const float* __restrict__ er,
    const float* __restrict__ ev, const float* __restrict__ fcw,
    const float* __restrict__ fcwQ, const float* __restrict__ fcb,
    const float* __restrict__ ws, float* __restrict__ out) {
  __shared__ _Float16 Bm[SPBM][128][40];   // 20 KB
  __shared__ float red[4];
  const int tid = threadIdx.x;
  const int base = blockIdx.x * SPBM;

  {  // B build: 256 jobs, one per thread
    const int s = tid >> 7, x = tid & 127;
    const int* xr = xb + (size_t)(base + s) * 10;
    const int x1 = (x + 1 < 128) ? x + 1 : 127;   // cols >= W_OUT masked by fcv
    const int x2 = (x + 2 < 128) ? x + 2 : 127;
    _Float16* dst = &Bm[s][x][0];
#pragma unroll
    for (int r = 0; r < 9; r++) {
      const float* hp = rowptr(xr, r, er, ev);
      dst[3 * r + 0] = (_Float16)hp[x];
      dst[3 * r + 1] = (_Float16)hp[x1];
      dst[3 * r + 2] = (_Float16)hp[x2];
    }
    dst[27] = (_Float16)1.0f;
#pragma unroll
    for (int k = 28; k < 40; k++) dst[k] = (_Float16)0.f;
  }
  __syncthreads();

  const int w = tid >> 6, l = tid & 63;
  const int s = w >> 1, mh = w & 1;               // sample, M-half (25 tiles)
  const int xl = l & 15, fl = l >> 4;
  const _Float16* __restrict__ Aw = (const _Float16*)ws + AW_OFF;
  const float4* __restrict__ fq4 = (const float4*)fcwQ;
  const float fcb0 = fcb[0];

  float psum = 0.f;
#pragma unroll 1
  for (int jh = 0; jh < 2; ++jh) {
    half8 bf[4];
#pragma unroll
    for (int j = 0; j < 4; ++j)                   // 4 N-tiles resident
      bf[j] = *(const half8*)&Bm[s][(jh * 4 + j) * 16 + xl][fl * 8];
#pragma unroll 1
    for (int mtb = 0; mtb < 5; ++mtb) {
      half8 af[5];
#pragma unroll
      for (int i = 0; i < 5; ++i) {               // 5 M-tiles per batch
        const int mtile = mh * 25 + mtb * 5 + i;
        af[i] = *(const half8*)&Aw[(size_t)(mtile * 16 + xl) * 32 + fl * 8];
      }
#pragma unroll
      for (int i = 0; i < 5; ++i) {
        const int mtile = mh * 25 + mtb * 5 + i;
        const int f = mtile * 4 + fl;             // < 200 always
        float4 fq;
        if (SWZ) fq = fq4[(mtile * 2 + jh) * 64 + l];   // coalesced 1KB/wave
#pragma unroll
        for (int j = 0; j < 4; ++j) {
          f32x4v acc = __builtin_amdgcn_mfma_f32_16x16x32_f16(
              af[i], bf[j], (f32x4v){0.f, 0.f, 0.f, 0.f}, 0, 0, 0);
          float fcv;
          if (SWZ) {
            fcv = (j == 0) ? fq.x : (j == 1) ? fq.y : (j == 2) ? fq.z : fq.w;
          } else {
            const int x = (jh * 4 + j) * 16 + xl;
            const bool xv = (x < W_OUT);
            const float fcl = fcw[(size_t)f * W_OUT + (xv ? x : 0)];
            fcv = xv ? fcl : 0.f;
          }
          float mv = fminf(fminf(acc[0], acc[1]), fminf(acc[2], acc[3]));
          psum = fmaf(fmaxf(mv, 0.f), fcv, psum); // min(relu)=relu(min)
        }
      }
    }
  }

#pragma unroll
  for (int off = 32; off; off >>= 1) psum += __shfl_xor(psum, off, 64);
  if (l == 0) red[w] = psum;
  __syncthreads();
  if (tid < SPBM)
    out[base + tid] = red[2 * tid] + red[2 * tid + 1] + fcb0;
}

extern "C" void kernel_launch(void* const* d_in, const int* in_sizes, int n_in,
                              void* d_out, int out_size, void* d_ws, size_t ws_size,
                              hipStream_t stream) {
  const int* xb    = (const int*)d_in[0];
  const float* er  = (const float*)d_in[3];
  const float* ev  = (const float*)d_in[4];
  const float* w1  = (const float*)d_in[5];
  const float* g1  = (const float*)d_in[7];
  const float* be1 = (const float*)d_in[8];
  const float* w2  = (const float*)d_in[9];
  const float* g2  = (const float*)d_in[11];
  const float* be2 = (const float*)d_in[12];
  const float* fcw = (const float*)d_in[13];
  const float* fcb = (const float*)d_in[14];
  float* ws  = (float*)d_ws;
  float* out = (float*)d_out;

  const int use_swz = (ws_size >= (size_t)WS_NEED) ? 1 : 0;
  float* fcwQ = (float*)((char*)d_ws + FCWQ_BYTE_OFF);

  // G32 scratch = out[0:1024) (overwritten by main afterwards)
  hipMemsetAsync(out, 0, 1024 * sizeof(float), stream);
  if (use_swz)
    hipLaunchKernelGGL(swizzle_fcw, dim3((FCWQ_FLOATS + 255) / 256), dim3(256),
                       0, stream, fcw, fcwQ);
  hipLaunchKernelGGL(stats_mfma, dim3(STATS_BLOCKS), dim3(256), 0, stream,
                     xb, er, ev, out);
  hipLaunchKernelGGL(finalize_kernel, dim3(1), dim3(256), 0, stream,
                     w1, w2, g1, be1, g2, be2, out, ws);
  if (use_swz)
    hipLaunchKernelGGL((main_mfma<true>), dim3(MAIN_BLOCKS), dim3(256), 0,
                       stream, xb, er, ev, fcw, fcwQ, fcb, ws, out);
  else
    hipLaunchKernelGGL((main_mfma<false>), dim3(MAIN_BLOCKS), dim3(256), 0,
                       stream, xb, er, ev, fcw, fcwQ, fcb, ws, out);
}

// Round 14
// 57.139 us; speedup vs baseline: 1.1026x; 1.0041x over previous
//
#include <hip/hip_runtime.h>

#define BB 2048
#define EMB 128
#define NF 200
#define W_OUT 126
#define EPS 1e-5f

// ws layout (bytes):
// [0, 51200)        A-matrix f16 (800 rows x 32 taps)
// [51200, 102400)   fcwQh: swizzled fc weights f16, [50][2][64][4]
// d_out[0:1024): G32 Gram scratch (memset -> stats atomics -> finalize),
//                fully overwritten by main afterwards.
#define AW_OFF 0
#define FCWQ_BYTE_OFF 51200
#define FCWQ_HALFS (50 * 2 * 64 * 4)    // 25600
#define WS_NEED (FCWQ_BYTE_OFF + FCWQ_HALFS * 2)

#define SPBS 4                    // stats: samples per block (wave <-> sample)
#define STATS_BLOCKS (BB / SPBS)  // 512
#define SPBM 2                    // main: samples per block (2 waves each)
#define MAIN_BLOCKS (BB / SPBM)   // 1024

typedef _Float16 half8 __attribute__((ext_vector_type(8)));
typedef _Float16 half4v __attribute__((ext_vector_type(4)));
typedef float f32x4v __attribute__((ext_vector_type(4)));

__device__ __forceinline__ const float* rowptr(const int* __restrict__ xr, int r,
                                               const float* __restrict__ er,
                                               const float* __restrict__ ev) {
  if (r == 0) return ev + (size_t)xr[1] * EMB;
  if (r == 1) return er + (size_t)xr[0] * EMB;
  if (r == 2) return ev + (size_t)xr[3] * EMB;
  const int k = (r - 3) >> 1;
  return ((r - 3) & 1) ? ev + (size_t)xr[5 + 2 * k] * EMB
                       : er + (size_t)xr[4 + 2 * k] * EMB;
}

// ---------------- stats: G32 = sum_s B_s^T B_s via MFMA (proven) ------------
__global__ __launch_bounds__(256, 2) void stats_mfma(
    const int* __restrict__ xb, const float* __restrict__ er,
    const float* __restrict__ ev, float* __restrict__ gout) {
  __shared__ _Float16 Bt[SPBS][40][136];   // 42.5 KB
  __shared__ float Gred[SPBS][1024];       // 16 KB
  const int tid = threadIdx.x;
  const int base = blockIdx.x * SPBS;

  for (int job = tid; job < SPBS * 136; job += 256) {
    const int s = job / 136, x = job % 136;
    if (x < W_OUT) {
      const int* xr = xb + (size_t)(base + s) * 10;
#pragma unroll
      for (int r = 0; r < 9; r++) {
        const float* hp = rowptr(xr, r, er, ev);
        Bt[s][3 * r + 0][x] = (_Float16)hp[x];
        Bt[s][3 * r + 1][x] = (_Float16)hp[x + 1];
        Bt[s][3 * r + 2][x] = (_Float16)hp[x + 2];
      }
      Bt[s][27][x] = (_Float16)1.0f;
#pragma unroll
      for (int k = 28; k < 40; k++) Bt[s][k][x] = (_Float16)0.f;
    } else {
#pragma unroll
      for (int k = 0; k < 40; k++) Bt[s][k][x] = (_Float16)0.f;
    }
  }
  __syncthreads();

  const int w = tid >> 6, l = tid & 63;
  const int tl = l & 15, kl = l >> 4;
  f32x4v a00 = {0.f, 0.f, 0.f, 0.f}, a01 = a00, a10 = a00, a11 = a00;
#pragma unroll
  for (int c = 0; c < 4; c++) {
    const int x0 = c * 32 + kl * 8;
    const half8 g0 = *(const half8*)&Bt[w][tl][x0];       // taps 0..15
    const half8 g1 = *(const half8*)&Bt[w][16 + tl][x0];  // taps 16..31
    a00 = __builtin_amdgcn_mfma_f32_16x16x32_f16(g0, g0, a00, 0, 0, 0);
    a01 = __builtin_amdgcn_mfma_f32_16x16x32_f16(g0, g1, a01, 0, 0, 0);
    a10 = __builtin_amdgcn_mfma_f32_16x16x32_f16(g1, g0, a10, 0, 0, 0);
    a11 = __builtin_amdgcn_mfma_f32_16x16x32_f16(g1, g1, a11, 0, 0, 0);
  }
  // D layout: row=(l>>4)*4+reg, col=l&15
#pragma unroll
  for (int r = 0; r < 4; r++) {
    const int rm = kl * 4 + r;
    Gred[w][rm * 32 + tl]             = a00[r];
    Gred[w][rm * 32 + 16 + tl]        = a01[r];
    Gred[w][(16 + rm) * 32 + tl]      = a10[r];
    Gred[w][(16 + rm) * 32 + 16 + tl] = a11[r];
  }
  __syncthreads();
  for (int idx = tid; idx < 1024; idx += 256) {
    float s = Gred[0][idx] + Gred[1][idx] + Gred[2][idx] + Gred[3][idx];
    atomicAdd(&gout[idx], s);
  }
}

// ---------------- fcw swizzle: bake MFMA lane order + masks, f16 ------------
__global__ __launch_bounds__(256) void swizzle_fcw(
    const float* __restrict__ fcw, _Float16* __restrict__ fcwQh) {
  const int idx = blockIdx.x * 256 + threadIdx.x;
  if (idx >= FCWQ_HALFS) return;
  const int mtile = idx >> 9;          // /512
  const int rem = idx & 511;
  const int jh = rem >> 8;             // /256
  const int rem2 = rem & 255;
  const int l = rem2 >> 2;
  const int j = rem2 & 3;
  const int f = mtile * 4 + (l >> 4);  // always < 200
  const int x = (jh * 4 + j) * 16 + (l & 15);
  fcwQh[idx] = (_Float16)((x < W_OUT) ? fcw[(size_t)f * W_OUT + x] : 0.f);
}

// ---------------- finalize: G32 -> BN params -> f16 A-matrix ----------------
__global__ __launch_bounds__(256) void finalize_kernel(
    const float* __restrict__ w1, const float* __restrict__ w2,
    const float* __restrict__ g1, const float* __restrict__ be1,
    const float* __restrict__ g2, const float* __restrict__ be2,
    const float* __restrict__ gbuf, float* __restrict__ ws) {
  __shared__ float G[1024];
  const int tid = threadIdx.x;
  for (int e = tid; e < 1024; e += 256) G[e] = gbuf[e];
  __syncthreads();
  const int f = tid;
  if (f >= NF) return;
  _Float16* Aw = (_Float16*)ws + AW_OFF;
  float w1r[9], w2r[15];
#pragma unroll
  for (int j = 0; j < 9; j++)  w1r[j] = w1[f * 9 + j];
#pragma unroll
  for (int j = 0; j < 15; j++) w2r[j] = w2[f * 15 + j];
  const float invN = 1.0f / (float)(BB * W_OUT);

  float m1 = 0.f, q1 = 0.f;
#pragma unroll
  for (int i = 0; i < 9; i++) {
    m1 = fmaf(w1r[i], G[i * 32 + 27], m1);
#pragma unroll
    for (int j = 0; j < 9; j++) q1 = fmaf(w1r[i] * w1r[j], G[i * 32 + j], q1);
  }
  m1 *= invN;
  float v1 = q1 * invN - m1 * m1;
  float sc1 = g1[f] * rsqrtf(v1 + EPS);
  float sh1 = be1[f] - m1 * sc1;
  {
    _Float16* rw = Aw + (size_t)(4 * f + 0) * 32;
#pragma unroll
    for (int k = 0; k < 32; k++) rw[k] = (_Float16)0.f;
#pragma unroll
    for (int i = 0; i < 9; i++) rw[i] = (_Float16)(w1r[i] * sc1);
    rw[27] = (_Float16)sh1;
  }

  float mcm = 0.f, qc = 0.f;
#pragma unroll
  for (int i = 0; i < 9; i++) {
    mcm = fmaf(w2r[i], G[i * 32 + 27], mcm);
#pragma unroll
    for (int j = 0; j < 9; j++) qc = fmaf(w2r[i] * w2r[j], G[i * 32 + j], qc);
  }
#pragma unroll
  for (int kk = 0; kk < 3; kk++) {
    const int a = 3 + 2 * kk, b = 4 + 2 * kk;
    float m2 = mcm, cross = 0.f, qa = 0.f, qb = 0.f, qab = 0.f;
#pragma unroll
    for (int j = 0; j < 3; j++) {
      m2 = fmaf(w2r[9 + j],  G[(3 * a + j) * 32 + 27], m2);
      m2 = fmaf(w2r[12 + j], G[(3 * b + j) * 32 + 27], m2);
    }
#pragma unroll
    for (int i = 0; i < 9; i++) {
      float t = 0.f;
#pragma unroll
      for (int j = 0; j < 3; j++) {
        t = fmaf(w2r[9 + j],  G[i * 32 + 3 * a + j], t);
        t = fmaf(w2r[12 + j], G[i * 32 + 3 * b + j], t);
      }
      cross = fmaf(w2r[i], t, cross);
    }
#pragma unroll
    for (int j = 0; j < 3; j++)
#pragma unroll
      for (int jp = 0; jp < 3; jp++) {
        qa  = fmaf(w2r[9 + j]  * w2r[9 + jp],  G[(3 * a + j) * 32 + 3 * a + jp], qa);
        qb  = fmaf(w2r[12 + j] * w2r[12 + jp], G[(3 * b + j) * 32 + 3 * b + jp], qb);
        qab = fmaf(w2r[9 + j]  * w2r[12 + jp], G[(3 * a + j) * 32 + 3 * b + jp], qab);
      }
    float q2 = qc + 2.f * cross + qa + qb + 2.f * qab;
    float mean2 = m2 * invN;
    float v2 = q2 * invN - mean2 * mean2;
    float sck = g2[f] * rsqrtf(v2 + EPS);
    float shk = be2[f] - mean2 * sck;

    _Float16* rw = Aw + (size_t)(4 * f + 1 + kk) * 32;
#pragma unroll
    for (int k = 0; k < 32; k++) rw[k] = (_Float16)0.f;
#pragma unroll
    for (int i = 0; i < 9; i++) rw[i] = (_Float16)(w2r[i] * sck);
#pragma unroll
    for (int j = 0; j < 3; j++) {
      rw[3 * a + j] = (_Float16)(w2r[9 + j]  * sck);
      rw[3 * b + j] = (_Float16)(w2r[12 + j] * sck);
    }
    rw[27] = (_Float16)shk;
  }
}

// ---------------- main: A staged in LDS, NT gathers, f16 fcwQ ---------------
template <bool SWZ>
__global__ __launch_bounds__(256, 2) void main_mfma(
    const int* __restrict__ xb, const float* __restrict__ er,
    const float* __restrict__ ev, const float* __restrict__ fcw,
    const _Float16* __restrict__ fcwQh, const float* __restrict__ fcb,
    const float* __restrict__ ws, float* __restrict__ out) {
  __shared__ _Float16 Af[800 * 32];        // 51.2 KB: whole A-matrix
  __shared__ _Float16 Bm[SPBM][128][40];   // 20.5 KB
  __shared__ float red[4];
  const int tid = threadIdx.x;
  const int base = blockIdx.x * SPBM;

  {  // stage A into LDS: coalesced 8B/lane, cacheable (L2-resident source)
    const uint2* __restrict__ Ag = (const uint2*)ws;
    uint2* Al = (uint2*)Af;
#pragma unroll
    for (int i = 0; i < 25; ++i) Al[tid + i * 256] = Ag[tid + i * 256];
  }
  {  // B build: one (s,x) per thread; NONTEMPORAL gathers (don't thrash L2)
    const int s = tid >> 7, x = tid & 127;
    const int* xr = xb + (size_t)(base + s) * 10;
    const int x1 = (x + 1 < 128) ? x + 1 : 127;   // cols >= W_OUT masked by fcv
    const int x2 = (x + 2 < 128) ? x + 2 : 127;
    _Float16* dst = &Bm[s][x][0];
#pragma unroll
    for (int r = 0; r < 9; r++) {
      const float* hp = rowptr(xr, r, er, ev);
      const float v0 = __builtin_nontemporal_load(hp + x);
      const float v1 = __builtin_nontemporal_load(hp + x1);
      const float v2 = __builtin_nontemporal_load(hp + x2);
      dst[3 * r + 0] = (_Float16)v0;
      dst[3 * r + 1] = (_Float16)v1;
      dst[3 * r + 2] = (_Float16)v2;
    }
    dst[27] = (_Float16)1.0f;
#pragma unroll
    for (int k = 28; k < 40; k++) dst[k] = (_Float16)0.f;
  }
  __syncthreads();

  const int w = tid >> 6, l = tid & 63;
  const int s = w >> 1, mh = w & 1;               // sample, M-half (25 tiles)
  const int xl = l & 15, fl = l >> 4;
  const float fcb0 = fcb[0];

  float psum = 0.f;
#pragma unroll 1
  for (int jh = 0; jh < 2; ++jh) {
    half8 bf[4];
#pragma unroll
    for (int j = 0; j < 4; ++j)                   // 4 N-tiles resident
      bf[j] = *(const half8*)&Bm[s][(jh * 4 + j) * 16 + xl][fl * 8];
#pragma unroll 1
    for (int mtb = 0; mtb < 5; ++mtb) {
      half8 af[5];
#pragma unroll
      for (int i = 0; i < 5; ++i) {               // 5 M-tiles from LDS
        const int mtile = mh * 25 + mtb * 5 + i;
        af[i] = *(const half8*)&Af[(size_t)(mtile * 16 + xl) * 32 + fl * 8];
      }
#pragma unroll
      for (int i = 0; i < 5; ++i) {
        const int mtile = mh * 25 + mtb * 5 + i;
        const int f = mtile * 4 + fl;             // < 200 always
        half4v fqh;
        if (SWZ)
          fqh = *(const half4v*)&fcwQh[((size_t)(mtile * 2 + jh) * 64 + l) * 4];
#pragma unroll
        for (int j = 0; j < 4; ++j) {
          f32x4v acc = __builtin_amdgcn_mfma_f32_16x16x32_f16(
              af[i], bf[j], (f32x4v){0.f, 0.f, 0.f, 0.f}, 0, 0, 0);
          float fcv;
          if (SWZ) {
            fcv = (float)fqh[j];
          } else {
            const int x = (jh * 4 + j) * 16 + xl;
            const bool xv = (x < W_OUT);
            const float fcl = fcw[(size_t)f * W_OUT + (xv ? x : 0)];
            fcv = xv ? fcl : 0.f;
          }
          float mv = fminf(fminf(acc[0], acc[1]), fminf(acc[2], acc[3]));
          psum = fmaf(fmaxf(mv, 0.f), fcv, psum); // min(relu)=relu(min)
        }
      }
    }
  }

#pragma unroll
  for (int off = 32; off; off >>= 1) psum += __shfl_xor(psum, off, 64);
  if (l == 0) red[w] = psum;
  __syncthreads();
  if (tid < SPBM)
    out[base + tid] = red[2 * tid] + red[2 * tid + 1] + fcb0;
}

extern "C" void kernel_launch(void* const* d_in, const int* in_sizes, int n_in,
                              void* d_out, int out_size, void* d_ws, size_t ws_size,
                              hipStream_t stream) {
  const int* xb    = (const int*)d_in[0];
  const float* er  = (const float*)d_in[3];
  const float* ev  = (const float*)d_in[4];
  const float* w1  = (const float*)d_in[5];
  const float* g1  = (const float*)d_in[7];
  const float* be1 = (const float*)d_in[8];
  const float* w2  = (const float*)d_in[9];
  const float* g2  = (const float*)d_in[11];
  const float* be2 = (const float*)d_in[12];
  const float* fcw = (const float*)d_in[13];
  const float* fcb = (const float*)d_in[14];
  float* ws  = (float*)d_ws;
  float* out = (float*)d_out;

  const int use_swz = (ws_size >= (size_t)WS_NEED) ? 1 : 0;
  _Float16* fcwQh = (_Float16*)((char*)d_ws + FCWQ_BYTE_OFF);

  // G32 scratch = out[0:1024) (overwritten by main afterwards)
  hipMemsetAsync(out, 0, 1024 * sizeof(float), stream);
  if (use_swz)
    hipLaunchKernelGGL(swizzle_fcw, dim3((FCWQ_HALFS + 255) / 256), dim3(256),
                       0, stream, fcw, fcwQh);
  hipLaunchKernelGGL(stats_mfma, dim3(STATS_BLOCKS), dim3(256), 0, stream,
                     xb, er, ev, out);
  hipLaunchKernelGGL(finalize_kernel, dim3(1), dim3(256), 0, stream,
                     w1, w2, g1, be1, g2, be2, out, ws);
  if (use_swz)
    hipLaunchKernelGGL((main_mfma<true>), dim3(MAIN_BLOCKS), dim3(256), 0,
                       stream, xb, er, ev, fcw, fcwQh, fcb, ws, out);
  else
    hipLaunchKernelGGL((main_mfma<false>), dim3(MAIN_BLOCKS), dim3(256), 0,
                       stream, xb, er, ev, fcw, fcwQh, fcb, ws, out);
}